// Round 4
// baseline (324.589 us; speedup 1.0000x reference)
//
#include <hip/hip_runtime.h>
#include <cstddef>

#define A_ATOMS 96
#define BATCH   128
#define NNODES  12288   // B*A
#define NB      16      // nodes per block
#define XS      196     // xin LDS stride (pad: 196%32=4)
#define WS      132     // work/x1/Cs LDS stride (pad: 132%32=4)

__device__ __forceinline__ float silu_f(float x) {
    float e = __expf(-x);
    return x * __builtin_amdgcn_rcpf(1.0f + e);
}

#define RED64(v) { v += __shfl_xor(v, 1); v += __shfl_xor(v, 2); v += __shfl_xor(v, 4); \
                   v += __shfl_xor(v, 8); v += __shfl_xor(v, 16); v += __shfl_xor(v, 32); }

// ===== fused node kernel: vmix GEMM + norm + MLP1 + block2 + P-tables =======
// 16 nodes (48 vrep rows) per block, 256 threads, 768 blocks (3/CU).
__global__ __launch_bounds__(256)
void node_k(const float* __restrict__ vrep, const float* __restrict__ mixW1,
            const float* __restrict__ srep,
            const float* __restrict__ sc1W1, const float* __restrict__ sc1b1,
            const float* __restrict__ sc1W2, const float* __restrict__ sc1b2,
            const float* __restrict__ mixW2,
            const float* __restrict__ sc2W1, const float* __restrict__ sc2b1,
            const float* __restrict__ sc2W2, const float* __restrict__ sc2b2,
            const float* __restrict__ pos,
            const float* __restrict__ vvW1, const float* __restrict__ vrW1,
            const float* __restrict__ sW1, const float* __restrict__ sb1,
            float* __restrict__ l0v, float* __restrict__ l1v,
            float* __restrict__ Pv, float* __restrict__ Pr,
            float* __restrict__ Ps) {
    __shared__ float As[8 * 48];        // stage1 A chunk (k-major)
    __shared__ float Bt[8 * 128];       // weight chunk (stages 1,3,4)
    __shared__ float Cs[48 * WS];       // vmix tile, lives to stage 5
    __shared__ float xinS[NB * XS];     // xin, then x1 (stride WS)
    __shared__ float workS[NB * WS];    // hmid
    __shared__ float s1s[4][64];
    __shared__ float l0s[NB];
    __shared__ float l1s[NB * 3];

    const int t  = threadIdx.x;
    const int tx = t & 15;              // col group: cols tx*8..+7
    const int ty = t >> 4;              // row group
    const int row0  = blockIdx.x * 48;  // vrep row base
    const int node0 = blockIdx.x * NB;

    // ---------- stage 1: Cs = vrep[48 rows] @ mixW1 (48x128) ----------
    {
        float acc[3][8];
#pragma unroll
        for (int i = 0; i < 3; i++)
#pragma unroll
            for (int j = 0; j < 8; j++) acc[i][j] = 0.0f;

        for (int kc = 0; kc < 128; kc += 8) {
            if (t < 96) {
                const int m  = t >> 1;
                const int k4 = (t & 1) * 4;
                float4 av = *(const float4*)(vrep + (size_t)(row0 + m) * 128 + kc + k4);
                As[(k4 + 0) * 48 + m] = av.x; As[(k4 + 1) * 48 + m] = av.y;
                As[(k4 + 2) * 48 + m] = av.z; As[(k4 + 3) * 48 + m] = av.w;
            }
            {
                const int kb = t >> 5;
                const int n4 = (t & 31) * 4;
                *(float4*)&Bt[kb * 128 + n4] = *(const float4*)(mixW1 + (size_t)(kc + kb) * 128 + n4);
            }
            __syncthreads();
#pragma unroll
            for (int k = 0; k < 8; k++) {
                float bf[8], af[3];
                *(float4*)&bf[0] = *(const float4*)&Bt[k * 128 + tx * 8];
                *(float4*)&bf[4] = *(const float4*)&Bt[k * 128 + tx * 8 + 4];
                af[0] = As[k * 48 + ty * 3 + 0];
                af[1] = As[k * 48 + ty * 3 + 1];
                af[2] = As[k * 48 + ty * 3 + 2];
#pragma unroll
                for (int i = 0; i < 3; i++)
#pragma unroll
                    for (int j = 0; j < 8; j++) acc[i][j] += af[i] * bf[j];
            }
            __syncthreads();
        }
#pragma unroll
        for (int i = 0; i < 3; i++) {
            const int m = ty * 3 + i;
            *(float4*)&Cs[m * WS + tx * 8]     = *(float4*)&acc[i][0];
            *(float4*)&Cs[m * WS + tx * 8 + 4] = *(float4*)&acc[i][4];
        }
    }
    __syncthreads();

    // ---------- stage 2: xin = [srep | norm(vV)] ----------
#pragma unroll
    for (int it = 0; it < 2; it++) {    // srep copy: 16x128 = 512 float4
        const int idx = it * 256 + t;
        const int a   = idx >> 5;
        const int c4  = (idx & 31) * 4;
        *(float4*)&xinS[a * XS + c4] =
            *(const float4*)(srep + (size_t)(node0 + a) * 128 + c4);
    }
#pragma unroll
    for (int it = 0; it < 4; it++) {    // norms: 16 nodes x 64 cols
        const int idx = it * 256 + t;
        const int a   = idx >> 6;
        const int c   = idx & 63;
        const float v0 = Cs[(3 * a + 0) * WS + c];
        const float v1 = Cs[(3 * a + 1) * WS + c];
        const float v2 = Cs[(3 * a + 2) * WS + c];
        xinS[a * XS + 128 + c] = sqrtf(v0 * v0 + v1 * v1 + v2 * v2);
    }
    __syncthreads();

    // ---------- stage 3: hmid = silu(xin @ sc1W1 + b1)  (16x192 @ 192x128) --
    {
        float acc3[8];
#pragma unroll
        for (int j = 0; j < 8; j++) acc3[j] = 0.0f;
        for (int kc = 0; kc < 192; kc += 8) {
            {
                const int kb = t >> 5;
                const int n4 = (t & 31) * 4;
                *(float4*)&Bt[kb * 128 + n4] = *(const float4*)(sc1W1 + (size_t)(kc + kb) * 128 + n4);
            }
            __syncthreads();
            float af[8];
            *(float4*)&af[0] = *(const float4*)&xinS[ty * XS + kc];
            *(float4*)&af[4] = *(const float4*)&xinS[ty * XS + kc + 4];
#pragma unroll
            for (int k = 0; k < 8; k++) {
                float bf[8];
                *(float4*)&bf[0] = *(const float4*)&Bt[k * 128 + tx * 8];
                *(float4*)&bf[4] = *(const float4*)&Bt[k * 128 + tx * 8 + 4];
#pragma unroll
                for (int j = 0; j < 8; j++) acc3[j] += af[k] * bf[j];
            }
            __syncthreads();
        }
#pragma unroll
        for (int j = 0; j < 8; j++)
            workS[ty * WS + tx * 8 + j] = silu_f(acc3[j] + sc1b1[tx * 8 + j]);
    }
    __syncthreads();

    // ---------- stage 4: x1 = hmid @ sc1W2 + b2  (16x128 @ 128x128) ---------
    {
        float acc4[8];
#pragma unroll
        for (int j = 0; j < 8; j++) acc4[j] = 0.0f;
        for (int kc = 0; kc < 128; kc += 8) {
            {
                const int kb = t >> 5;
                const int n4 = (t & 31) * 4;
                *(float4*)&Bt[kb * 128 + n4] = *(const float4*)(sc1W2 + (size_t)(kc + kb) * 128 + n4);
            }
            __syncthreads();
            float af[8];
            *(float4*)&af[0] = *(const float4*)&workS[ty * WS + kc];
            *(float4*)&af[4] = *(const float4*)&workS[ty * WS + kc + 4];
#pragma unroll
            for (int k = 0; k < 8; k++) {
                float bf[8];
                *(float4*)&bf[0] = *(const float4*)&Bt[k * 128 + tx * 8];
                *(float4*)&bf[4] = *(const float4*)&Bt[k * 128 + tx * 8 + 4];
#pragma unroll
                for (int j = 0; j < 8; j++) acc4[j] += af[k] * bf[j];
            }
            __syncthreads();
        }
#pragma unroll
        for (int j = 0; j < 8; j++)
            xinS[ty * WS + tx * 8 + j] = acc4[j] + sc1b2[tx * 8 + j];  // x1, stride WS
    }
    __syncthreads();

    // ---------- stage 5: block-1 epilogue + block-2 (glue2) per node --------
    {
        const int w = t >> 6, lane = t & 63;
        const float w0 = mixW2[lane * 2 + 0], w1 = mixW2[lane * 2 + 1];
        const float wq0 = sc2W2[lane * 2 + 0], wq1 = sc2W2[lane * 2 + 1];
        const float bb1 = sc2b1[lane];
        const float wn  = sc2W1[64 * 64 + lane];
#pragma unroll
        for (int r = 0; r < 4; r++) {
            const int nl = r * 4 + w;
            const float xa = xinS[nl * WS + lane];
            const float xb = xinS[nl * WS + 64 + lane];
            const float s1 = silu_f(xa);
            const float v1_0 = xb * Cs[(3 * nl + 0) * WS + 64 + lane];
            const float v1_1 = xb * Cs[(3 * nl + 1) * WS + 64 + lane];
            const float v1_2 = xb * Cs[(3 * nl + 2) * WS + 64 + lane];

            float p0 = v1_0 * w0, p1 = v1_0 * w1;
            float p2 = v1_1 * w0, p3 = v1_1 * w1;
            float p4 = v1_2 * w0, p5 = v1_2 * w1;
            RED64(p0); RED64(p1); RED64(p2); RED64(p3); RED64(p4); RED64(p5);
            const float vn2 = sqrtf(p0 * p0 + p2 * p2 + p4 * p4);

            s1s[w][lane] = s1;
            __builtin_amdgcn_s_waitcnt(0);   // lgkmcnt(0): own-wave LDS write visible
            float acc = bb1 + vn2 * wn;
            for (int i2 = 0; i2 < 64; i2++) acc += s1s[w][i2] * sc2W1[i2 * 64 + lane];
            const float h2 = silu_f(acc);

            float q0 = h2 * wq0;
            float q1 = h2 * wq1;
            RED64(q0); RED64(q1);

            if (lane == 0) {
                const int n = node0 + nl;
                const float s_out = q0 + sc2b2[0];
                const float gate  = q1 + sc2b2[1];
                l0v[n] = s_out;
                l1v[(size_t)n * 3 + 0] = gate * p1;
                l1v[(size_t)n * 3 + 1] = gate * p3;
                l1v[(size_t)n * 3 + 2] = gate * p5;
                l0s[nl] = s_out;
                l1s[nl * 3 + 0] = gate * p1;
                l1s[nl * 3 + 1] = gate * p3;
                l1s[nl * 3 + 2] = gate * p5;
            }
        }
    }
    __syncthreads();

    // ---------- stage 6: P-tables for these 16 nodes (pairpre) --------------
    {
        const int h = t & 31;
        if (h < 30) {
#pragma unroll
            for (int half = 0; half < 2; half++) {
                const int nl = (t >> 5) + half * 8;
                const int j  = node0 + nl;
                const float lj0 = l1s[nl * 3 + 0], lj1 = l1s[nl * 3 + 1], lj2 = l1s[nl * 3 + 2];
                const float pj0 = pos[j * 3 + 0], pj1 = pos[j * 3 + 1], pj2 = pos[j * 3 + 2];
#pragma unroll
                for (int a = 0; a < 3; a++) {
                    float v = lj0 * vvW1[(3 * a + 0) * 30 + h] + lj1 * vvW1[(3 * a + 1) * 30 + h]
                            + lj2 * vvW1[(3 * a + 2) * 30 + h];
                    float r = pj0 * vrW1[(3 * a + 0) * 30 + h] + pj1 * vrW1[(3 * a + 1) * 30 + h]
                            + pj2 * vrW1[(3 * a + 2) * 30 + h];
                    Pv[(size_t)(a * 30 + h) * NNODES + j] = v;
                    Pr[(size_t)(a * 30 + h) * NNODES + j] = r;
                }
                Ps[(size_t)h * NNODES + j] = sb1[h] + l0s[nl] * sW1[30 + h];
            }
        }
    }
}

// ---------------- pair kernel: factorized MLPs, rolled h-loops --------------
__global__ __launch_bounds__(192)
void pair_k(const float* __restrict__ l0v, const float* __restrict__ l1v,
            const float* __restrict__ Pv, const float* __restrict__ Pr,
            const float* __restrict__ Ps,
            const float* __restrict__ vvb1, const float* __restrict__ vrb1,
            const float* __restrict__ sW1,
            const float* __restrict__ vvW2, const float* __restrict__ vrW2,
            const float* __restrict__ sW2,
            const float* __restrict__ vvb2, const float* __restrict__ vrb2,
            const float* __restrict__ sb2,
            const float* __restrict__ hW1,  const float* __restrict__ hb1,
            const float* __restrict__ hW2,  const float* __restrict__ hb2,
            float* __restrict__ out) {
    const int t = threadIdx.x;
    const int b = blockIdx.y;
    const int di = (t >= 96) ? 1 : 0;
    const int i = blockIdx.x * 2 + di;
    const int j = t - di * 96;
    const int ni = b * A_ATOMS + i;
    const int nj = b * A_ATOMS + j;

    const float li0 = l1v[ni * 3 + 0], li1 = l1v[ni * 3 + 1], li2 = l1v[ni * 3 + 2];
    const float s0i = l0v[ni];

    float t9[9];
#pragma unroll
    for (int l = 0; l < 9; l++) t9[l] = vvb2[l] + vrb2[l] + sb2[l];

    for (int h = 0; h < 30; h++) {
        float av = vvb1[h] + li0 * Pv[(size_t)h * NNODES + nj]
                           + li1 * Pv[(size_t)(30 + h) * NNODES + nj]
                           + li2 * Pv[(size_t)(60 + h) * NNODES + nj];
        float ar = vrb1[h] + li0 * Pr[(size_t)h * NNODES + nj]
                           + li1 * Pr[(size_t)(30 + h) * NNODES + nj]
                           + li2 * Pr[(size_t)(60 + h) * NNODES + nj];
        float as = Ps[(size_t)h * NNODES + nj] + s0i * sW1[h];
        av = silu_f(av); ar = silu_f(ar); as = silu_f(as);
#pragma unroll
        for (int l = 0; l < 9; l++)
            t9[l] += av * vvW2[h * 9 + l] + ar * vrW2[h * 9 + l] + as * sW2[h * 9 + l];
    }

    float o9[9];
#pragma unroll
    for (int l = 0; l < 9; l++) o9[l] = hb2[l];
    for (int h = 0; h < 30; h++) {
        float a = hb1[h];
#pragma unroll
        for (int m = 0; m < 9; m++) a += t9[m] * hW1[m * 30 + h];
        a = silu_f(a);
#pragma unroll
        for (int l = 0; l < 9; l++) o9[l] += a * hW2[h * 9 + l];
    }

    // out[((b*A+i)*3+k)*288 + j*3 + l] = o9[3k+l]
    const size_t rb = (size_t)(b * A_ATOMS + i);
#pragma unroll
    for (int k = 0; k < 3; k++) {
        const size_t off = (rb * 3 + k) * 288 + (size_t)j * 3;
        out[off + 0] = o9[3 * k + 0];
        out[off + 1] = o9[3 * k + 1];
        out[off + 2] = o9[3 * k + 2];
    }
}

extern "C" void kernel_launch(void* const* d_in, const int* in_sizes, int n_in,
                              void* d_out, int out_size, void* d_ws, size_t ws_size,
                              hipStream_t stream) {
    const float* pos   = (const float*)d_in[0];
    const float* srep  = (const float*)d_in[1];
    const float* vrep  = (const float*)d_in[2];
    const float* mixW1 = (const float*)d_in[3];
    const float* sc1W1 = (const float*)d_in[4];
    const float* sc1b1 = (const float*)d_in[5];
    const float* sc1W2 = (const float*)d_in[6];
    const float* sc1b2 = (const float*)d_in[7];
    const float* mixW2 = (const float*)d_in[8];
    const float* sc2W1 = (const float*)d_in[9];
    const float* sc2b1 = (const float*)d_in[10];
    const float* sc2W2 = (const float*)d_in[11];
    const float* sc2b2 = (const float*)d_in[12];
    const float* vvW1  = (const float*)d_in[13];
    const float* vvb1  = (const float*)d_in[14];
    const float* vvW2  = (const float*)d_in[15];
    const float* vvb2  = (const float*)d_in[16];
    const float* vrW1  = (const float*)d_in[17];
    const float* vrb1  = (const float*)d_in[18];
    const float* vrW2  = (const float*)d_in[19];
    const float* vrb2  = (const float*)d_in[20];
    const float* sW1   = (const float*)d_in[21];
    const float* sb1   = (const float*)d_in[22];
    const float* sW2   = (const float*)d_in[23];
    const float* sb2   = (const float*)d_in[24];
    const float* hW1   = (const float*)d_in[25];
    const float* hb1   = (const float*)d_in[26];
    const float* hW2   = (const float*)d_in[27];
    const float* hb2   = (const float*)d_in[28];

    float* ws  = (float*)d_ws;
    float* Pv  = ws;                    // 90*12288 = 1,105,920
    float* Pr  = Pv + 1105920;          // 1,105,920
    float* Ps  = Pr + 1105920;          // 30*12288 = 368,640
    float* l0v = Ps + 368640;           // 12,288
    float* l1v = l0v + 12288;           // 36,864
    float* outf = (float*)d_out;

    // 1. fused node stage (everything per-node) -> l0, l1, P-tables
    node_k<<<NNODES / NB, 256, 0, stream>>>(
        vrep, mixW1, srep,
        sc1W1, sc1b1, sc1W2, sc1b2,
        mixW2, sc2W1, sc2b1, sc2W2, sc2b2,
        pos, vvW1, vrW1, sW1, sb1,
        l0v, l1v, Pv, Pr, Ps);

    // 2. pair stage
    pair_k<<<dim3(A_ATOMS / 2, BATCH), 192, 0, stream>>>(
        l0v, l1v, Pv, Pr, Ps,
        vvb1, vrb1, sW1,
        vvW2, vrW2, sW2,
        vvb2, vrb2, sb2,
        hW1, hb1, hW2, hb2,
        outf);
}

// Round 5
// 319.985 us; speedup vs baseline: 1.0144x; 1.0144x over previous
//
#include <hip/hip_runtime.h>
#include <cstddef>

#define A_ATOMS 96
#define BATCH   128
#define NNODES  12288   // B*A
#define NB      16      // nodes per block
#define AS      132     // AsL / workS stride (132%32=4 -> ty*4 banks)
#define XS      196     // xinS stride (196%32=4)

__device__ __forceinline__ float silu_f(float x) {
    float e = __expf(-x);
    return x * __builtin_amdgcn_rcpf(1.0f + e);
}

#define RED64(v) { v += __shfl_xor(v, 1); v += __shfl_xor(v, 2); v += __shfl_xor(v, 4); \
                   v += __shfl_xor(v, 8); v += __shfl_xor(v, 16); v += __shfl_xor(v, 32); }
#define RED16(v) { v += __shfl_xor(v, 1); v += __shfl_xor(v, 2); v += __shfl_xor(v, 4); \
                   v += __shfl_xor(v, 8); }

// ===== fused node kernel v2: weights from L2, ~6 barriers, register norms ===
// 16 nodes (48 vrep rows) per block, 256 threads, 768 blocks (3/CU, 4 max).
// Thread (tx,ty): node ty, spatial rows 3ty..3ty+2, cols {tx*4..+3, 64+tx*4..+3}.
__global__ __launch_bounds__(256)
void node_k(const float* __restrict__ vrep, const float* __restrict__ mixW1,
            const float* __restrict__ srep,
            const float* __restrict__ sc1W1, const float* __restrict__ sc1b1,
            const float* __restrict__ sc1W2, const float* __restrict__ sc1b2,
            const float* __restrict__ mixW2,
            const float* __restrict__ sc2W1, const float* __restrict__ sc2b1,
            const float* __restrict__ sc2W2, const float* __restrict__ sc2b2,
            const float* __restrict__ pos,
            const float* __restrict__ vvW1, const float* __restrict__ vrW1,
            const float* __restrict__ sW1, const float* __restrict__ sb1,
            float* __restrict__ l0v, float* __restrict__ l1v,
            float* __restrict__ Pv, float* __restrict__ Pr,
            float* __restrict__ Ps) {
    __shared__ float AsL[48 * AS];      // 25.3 KB; aliased as workS (hmid) later
    __shared__ float xinS[NB * XS];     // 12.5 KB: xin, then x1 (s-half)
    __shared__ float s1s[4][64];
    __shared__ float vn2s[NB];
    __shared__ float pw2s[NB][3];
    __shared__ float l0s[NB];
    __shared__ float l1s[NB * 3];

    const int t  = threadIdx.x;
    const int tx = t & 15;
    const int ty = t >> 4;
    const int row0  = blockIdx.x * 48;
    const int node0 = blockIdx.x * NB;

    // ---------- stage 0: load A-tile (48x128) + srep into LDS, one barrier --
#pragma unroll
    for (int it = 0; it < 6; it++) {
        const int idx = it * 256 + t;           // float4 index, 1536 total
        const int r   = idx >> 5;
        const int c4  = (idx & 31) * 4;
        *(float4*)&AsL[r * AS + c4] = *(const float4*)(vrep + (size_t)(row0 + r) * 128 + c4);
    }
#pragma unroll
    for (int it = 0; it < 2; it++) {            // srep: 16x128 = 512 float4
        const int idx = it * 256 + t;
        const int a   = idx >> 5;
        const int c4  = (idx & 31) * 4;
        *(float4*)&xinS[a * XS + c4] = *(const float4*)(srep + (size_t)(node0 + a) * 128 + c4);
    }
    __syncthreads();

    // ---------- stage 1: vmix rows 3ty..+2, cols {tx*4, 64+tx*4} ------------
    float acc[3][8];
#pragma unroll
    for (int i = 0; i < 3; i++)
#pragma unroll
        for (int j = 0; j < 8; j++) acc[i][j] = 0.0f;

    for (int kc = 0; kc < 128; kc += 4) {
        float a0[4], a1[4], a2[4];
        *(float4*)a0 = *(const float4*)&AsL[(3 * ty + 0) * AS + kc];
        *(float4*)a1 = *(const float4*)&AsL[(3 * ty + 1) * AS + kc];
        *(float4*)a2 = *(const float4*)&AsL[(3 * ty + 2) * AS + kc];
#pragma unroll
        for (int kk = 0; kk < 4; kk++) {
            float b0[4], b1[4];
            *(float4*)b0 = *(const float4*)(mixW1 + (size_t)(kc + kk) * 128 + tx * 4);
            *(float4*)b1 = *(const float4*)(mixW1 + (size_t)(kc + kk) * 128 + 64 + tx * 4);
#pragma unroll
            for (int j = 0; j < 4; j++) {
                acc[0][j]     += a0[kk] * b0[j];
                acc[1][j]     += a1[kk] * b0[j];
                acc[2][j]     += a2[kk] * b0[j];
                acc[0][4 + j] += a0[kk] * b1[j];
                acc[1][4 + j] += a1[kk] * b1[j];
                acc[2][4 + j] += a2[kk] * b1[j];
            }
        }
    }
    // norms of vV (cols tx*4..+3) entirely in-register
    {
        float nrm[4];
#pragma unroll
        for (int c = 0; c < 4; c++)
            nrm[c] = sqrtf(acc[0][c] * acc[0][c] + acc[1][c] * acc[1][c]
                         + acc[2][c] * acc[2][c]);
        *(float4*)&xinS[ty * XS + 128 + tx * 4] = *(float4*)nrm;
    }
    // keep vW half (cols 64+tx*4..+3) live through stages 3-4
    float accW[3][4];
#pragma unroll
    for (int i = 0; i < 3; i++)
#pragma unroll
        for (int c = 0; c < 4; c++) accW[i][c] = acc[i][4 + c];
    __syncthreads();

    // ---------- stage 3: hmid = silu(xin @ sc1W1 + b1), K=192 ---------------
    float* workS = AsL;                  // AsL dead; alias as hmid (16 x AS)
    {
        float acc3[8];
#pragma unroll
        for (int j = 0; j < 8; j++) acc3[j] = 0.0f;
        for (int kc = 0; kc < 192; kc += 4) {
            float af[4];
            *(float4*)af = *(const float4*)&xinS[ty * XS + kc];
#pragma unroll
            for (int kk = 0; kk < 4; kk++) {
                float b0[4], b1[4];
                *(float4*)b0 = *(const float4*)(sc1W1 + (size_t)(kc + kk) * 128 + tx * 4);
                *(float4*)b1 = *(const float4*)(sc1W1 + (size_t)(kc + kk) * 128 + 64 + tx * 4);
#pragma unroll
                for (int j = 0; j < 4; j++) {
                    acc3[j]     += af[kk] * b0[j];
                    acc3[4 + j] += af[kk] * b1[j];
                }
            }
        }
        float h0[4], h1[4];
#pragma unroll
        for (int j = 0; j < 4; j++) {
            h0[j] = silu_f(acc3[j]     + sc1b1[tx * 4 + j]);
            h1[j] = silu_f(acc3[4 + j] + sc1b1[64 + tx * 4 + j]);
        }
        *(float4*)&workS[ty * AS + tx * 4]      = *(float4*)h0;
        *(float4*)&workS[ty * AS + 64 + tx * 4] = *(float4*)h1;
    }
    __syncthreads();

    // ---------- stage 4: x1 = hmid @ sc1W2 + b2, K=128 ----------------------
    float xg[4];                         // x1 gate cols (64+tx*4..+3) stay in regs
    {
        float acc4[8];
#pragma unroll
        for (int j = 0; j < 8; j++) acc4[j] = 0.0f;
        for (int kc = 0; kc < 128; kc += 4) {
            float af[4];
            *(float4*)af = *(const float4*)&workS[ty * AS + kc];
#pragma unroll
            for (int kk = 0; kk < 4; kk++) {
                float b0[4], b1[4];
                *(float4*)b0 = *(const float4*)(sc1W2 + (size_t)(kc + kk) * 128 + tx * 4);
                *(float4*)b1 = *(const float4*)(sc1W2 + (size_t)(kc + kk) * 128 + 64 + tx * 4);
#pragma unroll
                for (int j = 0; j < 4; j++) {
                    acc4[j]     += af[kk] * b0[j];
                    acc4[4 + j] += af[kk] * b1[j];
                }
            }
        }
        float xs[4];
#pragma unroll
        for (int j = 0; j < 4; j++) {
            xs[j] = acc4[j] + sc1b2[tx * 4 + j];              // s-half -> LDS
            xg[j] = acc4[4 + j] + sc1b2[64 + tx * 4 + j];     // gate -> regs
        }
        *(float4*)&xinS[ty * XS + tx * 4] = *(float4*)xs;     // x1 s-cols 0..63
    }

    // ---------- stage 5a: mixW2 reduction in registers + 16-lane shfl -------
    {
        float mw0[4], mw1[4];
#pragma unroll
        for (int c = 0; c < 4; c++) {
            float2 m = *(const float2*)(mixW2 + (size_t)(tx * 4 + c) * 2);
            mw0[c] = m.x; mw1[c] = m.y;
        }
        float p0 = 0, p1 = 0, p2 = 0, p3 = 0, p4 = 0, p5 = 0;
#pragma unroll
        for (int c = 0; c < 4; c++) {
            const float v0 = xg[c] * accW[0][c];
            const float v1 = xg[c] * accW[1][c];
            const float v2 = xg[c] * accW[2][c];
            p0 += v0 * mw0[c]; p1 += v0 * mw1[c];
            p2 += v1 * mw0[c]; p3 += v1 * mw1[c];
            p4 += v2 * mw0[c]; p5 += v2 * mw1[c];
        }
        RED16(p0); RED16(p1); RED16(p2); RED16(p3); RED16(p4); RED16(p5);
        if (tx == 0) {
            vn2s[ty] = sqrtf(p0 * p0 + p2 * p2 + p4 * p4);
            pw2s[ty][0] = p1; pw2s[ty][1] = p3; pw2s[ty][2] = p5;
        }
    }
    __syncthreads();

    // ---------- stage 5b: block-2 MLP (64-wide) per node --------------------
    {
        const int w = t >> 6, lane = t & 63;
        const float bb1 = sc2b1[lane];
        const float wn  = sc2W1[64 * 64 + lane];
        const float wq0 = sc2W2[lane * 2 + 0], wq1 = sc2W2[lane * 2 + 1];
#pragma unroll
        for (int r = 0; r < 4; r++) {
            const int nl = r * 4 + w;
            const float s1 = silu_f(xinS[nl * XS + lane]);    // x1 s-cols
            s1s[w][lane] = s1;
            __builtin_amdgcn_s_waitcnt(0);   // lgkmcnt(0): own-wave LDS visible
            float acc5 = bb1 + vn2s[nl] * wn;
            for (int i2 = 0; i2 < 64; i2++) acc5 += s1s[w][i2] * sc2W1[i2 * 64 + lane];
            const float h2 = silu_f(acc5);
            float q0 = h2 * wq0, q1 = h2 * wq1;
            RED64(q0); RED64(q1);
            if (lane == 0) {
                const int n = node0 + nl;
                const float s_out = q0 + sc2b2[0];
                const float gate  = q1 + sc2b2[1];
                l0v[n] = s_out;
                l1v[(size_t)n * 3 + 0] = gate * pw2s[nl][0];
                l1v[(size_t)n * 3 + 1] = gate * pw2s[nl][1];
                l1v[(size_t)n * 3 + 2] = gate * pw2s[nl][2];
                l0s[nl] = s_out;
                l1s[nl * 3 + 0] = gate * pw2s[nl][0];
                l1s[nl * 3 + 1] = gate * pw2s[nl][1];
                l1s[nl * 3 + 2] = gate * pw2s[nl][2];
            }
        }
    }
    __syncthreads();

    // ---------- stage 6: P-tables for these 16 nodes ------------------------
    {
        const int h = t & 31;
        if (h < 30) {
#pragma unroll
            for (int half = 0; half < 2; half++) {
                const int nl = (t >> 5) + half * 8;
                const int j  = node0 + nl;
                const float lj0 = l1s[nl * 3 + 0], lj1 = l1s[nl * 3 + 1], lj2 = l1s[nl * 3 + 2];
                const float pj0 = pos[j * 3 + 0], pj1 = pos[j * 3 + 1], pj2 = pos[j * 3 + 2];
#pragma unroll
                for (int a = 0; a < 3; a++) {
                    float v = lj0 * vvW1[(3 * a + 0) * 30 + h] + lj1 * vvW1[(3 * a + 1) * 30 + h]
                            + lj2 * vvW1[(3 * a + 2) * 30 + h];
                    float r = pj0 * vrW1[(3 * a + 0) * 30 + h] + pj1 * vrW1[(3 * a + 1) * 30 + h]
                            + pj2 * vrW1[(3 * a + 2) * 30 + h];
                    Pv[(size_t)(a * 30 + h) * NNODES + j] = v;
                    Pr[(size_t)(a * 30 + h) * NNODES + j] = r;
                }
                Ps[(size_t)h * NNODES + j] = sb1[h] + l0s[nl] * sW1[30 + h];
            }
        }
    }
}

// ---------------- pair kernel: factorized MLPs, rolled h-loops --------------
__global__ __launch_bounds__(192)
void pair_k(const float* __restrict__ l0v, const float* __restrict__ l1v,
            const float* __restrict__ Pv, const float* __restrict__ Pr,
            const float* __restrict__ Ps,
            const float* __restrict__ vvb1, const float* __restrict__ vrb1,
            const float* __restrict__ sW1,
            const float* __restrict__ vvW2, const float* __restrict__ vrW2,
            const float* __restrict__ sW2,
            const float* __restrict__ vvb2, const float* __restrict__ vrb2,
            const float* __restrict__ sb2,
            const float* __restrict__ hW1,  const float* __restrict__ hb1,
            const float* __restrict__ hW2,  const float* __restrict__ hb2,
            float* __restrict__ out) {
    const int t = threadIdx.x;
    const int b = blockIdx.y;
    const int di = (t >= 96) ? 1 : 0;
    const int i = blockIdx.x * 2 + di;
    const int j = t - di * 96;
    const int ni = b * A_ATOMS + i;
    const int nj = b * A_ATOMS + j;

    const float li0 = l1v[ni * 3 + 0], li1 = l1v[ni * 3 + 1], li2 = l1v[ni * 3 + 2];
    const float s0i = l0v[ni];

    float t9[9];
#pragma unroll
    for (int l = 0; l < 9; l++) t9[l] = vvb2[l] + vrb2[l] + sb2[l];

    for (int h = 0; h < 30; h++) {
        float av = vvb1[h] + li0 * Pv[(size_t)h * NNODES + nj]
                           + li1 * Pv[(size_t)(30 + h) * NNODES + nj]
                           + li2 * Pv[(size_t)(60 + h) * NNODES + nj];
        float ar = vrb1[h] + li0 * Pr[(size_t)h * NNODES + nj]
                           + li1 * Pr[(size_t)(30 + h) * NNODES + nj]
                           + li2 * Pr[(size_t)(60 + h) * NNODES + nj];
        float as = Ps[(size_t)h * NNODES + nj] + s0i * sW1[h];
        av = silu_f(av); ar = silu_f(ar); as = silu_f(as);
#pragma unroll
        for (int l = 0; l < 9; l++)
            t9[l] += av * vvW2[h * 9 + l] + ar * vrW2[h * 9 + l] + as * sW2[h * 9 + l];
    }

    float o9[9];
#pragma unroll
    for (int l = 0; l < 9; l++) o9[l] = hb2[l];
    for (int h = 0; h < 30; h++) {
        float a = hb1[h];
#pragma unroll
        for (int m = 0; m < 9; m++) a += t9[m] * hW1[m * 30 + h];
        a = silu_f(a);
#pragma unroll
        for (int l = 0; l < 9; l++) o9[l] += a * hW2[h * 9 + l];
    }

    // out[((b*A+i)*3+k)*288 + j*3 + l] = o9[3k+l]
    const size_t rb = (size_t)(b * A_ATOMS + i);
#pragma unroll
    for (int k = 0; k < 3; k++) {
        const size_t off = (rb * 3 + k) * 288 + (size_t)j * 3;
        out[off + 0] = o9[3 * k + 0];
        out[off + 1] = o9[3 * k + 1];
        out[off + 2] = o9[3 * k + 2];
    }
}

extern "C" void kernel_launch(void* const* d_in, const int* in_sizes, int n_in,
                              void* d_out, int out_size, void* d_ws, size_t ws_size,
                              hipStream_t stream) {
    const float* pos   = (const float*)d_in[0];
    const float* srep  = (const float*)d_in[1];
    const float* vrep  = (const float*)d_in[2];
    const float* mixW1 = (const float*)d_in[3];
    const float* sc1W1 = (const float*)d_in[4];
    const float* sc1b1 = (const float*)d_in[5];
    const float* sc1W2 = (const float*)d_in[6];
    const float* sc1b2 = (const float*)d_in[7];
    const float* mixW2 = (const float*)d_in[8];
    const float* sc2W1 = (const float*)d_in[9];
    const float* sc2b1 = (const float*)d_in[10];
    const float* sc2W2 = (const float*)d_in[11];
    const float* sc2b2 = (const float*)d_in[12];
    const float* vvW1  = (const float*)d_in[13];
    const float* vvb1  = (const float*)d_in[14];
    const float* vvW2  = (const float*)d_in[15];
    const float* vvb2  = (const float*)d_in[16];
    const float* vrW1  = (const float*)d_in[17];
    const float* vrb1  = (const float*)d_in[18];
    const float* vrW2  = (const float*)d_in[19];
    const float* vrb2  = (const float*)d_in[20];
    const float* sW1   = (const float*)d_in[21];
    const float* sb1   = (const float*)d_in[22];
    const float* sW2   = (const float*)d_in[23];
    const float* sb2   = (const float*)d_in[24];
    const float* hW1   = (const float*)d_in[25];
    const float* hb1   = (const float*)d_in[26];
    const float* hW2   = (const float*)d_in[27];
    const float* hb2   = (const float*)d_in[28];

    float* ws  = (float*)d_ws;
    float* Pv  = ws;                    // 90*12288 = 1,105,920
    float* Pr  = Pv + 1105920;          // 1,105,920
    float* Ps  = Pr + 1105920;          // 30*12288 = 368,640
    float* l0v = Ps + 368640;           // 12,288
    float* l1v = l0v + 12288;           // 36,864
    float* outf = (float*)d_out;

    // 1. fused node stage (everything per-node) -> l0, l1, P-tables
    node_k<<<NNODES / NB, 256, 0, stream>>>(
        vrep, mixW1, srep,
        sc1W1, sc1b1, sc1W2, sc1b2,
        mixW2, sc2W1, sc2b1, sc2W2, sc2b2,
        pos, vvW1, vrW1, sW1, sb1,
        l0v, l1v, Pv, Pr, Ps);

    // 2. pair stage
    pair_k<<<dim3(A_ATOMS / 2, BATCH), 192, 0, stream>>>(
        l0v, l1v, Pv, Pr, Ps,
        vvb1, vrb1, sW1,
        vvW2, vrW2, sW2,
        vvb2, vrb2, sb2,
        hW1, hb1, hW2, hb2,
        outf);
}

// Round 6
// 319.819 us; speedup vs baseline: 1.0149x; 1.0005x over previous
//
#include <hip/hip_runtime.h>
#include <cstddef>

#define A_ATOMS 96
#define BATCH   128
#define NNODES  12288   // B*A
#define NB      8       // nodes per block
#define AS      132     // AsL / workS stride (132%32=4)
#define XS      196     // xinS stride (196%32=4)

__device__ __forceinline__ float silu_f(float x) {
    float e = __expf(-x);
    return x * __builtin_amdgcn_rcpf(1.0f + e);
}

#define RED64(v) { v += __shfl_xor(v, 1); v += __shfl_xor(v, 2); v += __shfl_xor(v, 4); \
                   v += __shfl_xor(v, 8); v += __shfl_xor(v, 16); v += __shfl_xor(v, 32); }
#define RED16(v) { v += __shfl_xor(v, 1); v += __shfl_xor(v, 2); v += __shfl_xor(v, 4); \
                   v += __shfl_xor(v, 8); }

// ===== fused node kernel v3: 8 nodes/block, 1536 blocks (6/CU), 4 barriers ==
// Thread (tx,ty), tx 0..31, ty 0..7: node ty, spatial rows 3ty..+2, cols tx*4..+3.
__global__ __launch_bounds__(256)
void node_k(const float* __restrict__ vrep, const float* __restrict__ mixW1,
            const float* __restrict__ srep,
            const float* __restrict__ sc1W1, const float* __restrict__ sc1b1,
            const float* __restrict__ sc1W2, const float* __restrict__ sc1b2,
            const float* __restrict__ mixW2,
            const float* __restrict__ sc2W1, const float* __restrict__ sc2b1,
            const float* __restrict__ sc2W2, const float* __restrict__ sc2b2,
            float* __restrict__ l0v, float* __restrict__ l1v) {
    __shared__ float AsL[24 * AS];      // 12.7 KB; aliased as workS (hmid) later
    __shared__ float xinS[NB * XS];     // 6.3 KB: xin, then x1 s-half
    __shared__ float s1s[4][64];
    __shared__ float vn2s[NB];
    __shared__ float pw2s[NB][3];

    const int t  = threadIdx.x;
    const int tx = t & 31;
    const int ty = t >> 5;
    const int row0  = blockIdx.x * 24;
    const int node0 = blockIdx.x * NB;

    // ---------- stage 0: vrep tile (24x128) + srep (8x128) into LDS ---------
#pragma unroll
    for (int it = 0; it < 3; it++) {
        const int idx = it * 256 + t;           // 768 float4
        const int r   = idx >> 5;
        const int c4  = (idx & 31) * 4;
        *(float4*)&AsL[r * AS + c4] = *(const float4*)(vrep + (size_t)(row0 + r) * 128 + c4);
    }
    {
        const int a  = t >> 5;
        const int c4 = (t & 31) * 4;
        *(float4*)&xinS[a * XS + c4] = *(const float4*)(srep + (size_t)(node0 + a) * 128 + c4);
    }
    __syncthreads();

    // ---------- stage 1: vmix rows 3ty..+2, cols tx*4..+3 -------------------
    float acc[3][4];                    // W-col threads keep this live to 5a
#pragma unroll
    for (int i = 0; i < 3; i++)
#pragma unroll
        for (int j = 0; j < 4; j++) acc[i][j] = 0.0f;

    for (int kc = 0; kc < 128; kc += 8) {
        float a0[8], a1[8], a2[8];
        *(float4*)&a0[0] = *(const float4*)&AsL[(3 * ty + 0) * AS + kc];
        *(float4*)&a0[4] = *(const float4*)&AsL[(3 * ty + 0) * AS + kc + 4];
        *(float4*)&a1[0] = *(const float4*)&AsL[(3 * ty + 1) * AS + kc];
        *(float4*)&a1[4] = *(const float4*)&AsL[(3 * ty + 1) * AS + kc + 4];
        *(float4*)&a2[0] = *(const float4*)&AsL[(3 * ty + 2) * AS + kc];
        *(float4*)&a2[4] = *(const float4*)&AsL[(3 * ty + 2) * AS + kc + 4];
#pragma unroll
        for (int kk = 0; kk < 8; kk++) {
            float b[4];
            *(float4*)b = *(const float4*)(mixW1 + (size_t)(kc + kk) * 128 + tx * 4);
#pragma unroll
            for (int j = 0; j < 4; j++) {
                acc[0][j] += a0[kk] * b[j];
                acc[1][j] += a1[kk] * b[j];
                acc[2][j] += a2[kk] * b[j];
            }
        }
    }
    if (tx < 16) {                      // V half: norms -> xin cols 128..191
        float nrm[4];
#pragma unroll
        for (int c = 0; c < 4; c++)
            nrm[c] = sqrtf(acc[0][c] * acc[0][c] + acc[1][c] * acc[1][c]
                         + acc[2][c] * acc[2][c]);
        *(float4*)&xinS[ty * XS + 128 + tx * 4] = *(float4*)nrm;
    }
    __syncthreads();

    // ---------- stage 3: hmid = silu(xin @ sc1W1 + b1), K=192 ---------------
    float* workS = AsL;                 // AsL dead; alias as hmid (8 x AS)
    {
        float acc3[4];
#pragma unroll
        for (int j = 0; j < 4; j++) acc3[j] = 0.0f;
        for (int kc = 0; kc < 192; kc += 8) {
            float af[8];
            *(float4*)&af[0] = *(const float4*)&xinS[ty * XS + kc];
            *(float4*)&af[4] = *(const float4*)&xinS[ty * XS + kc + 4];
#pragma unroll
            for (int kk = 0; kk < 8; kk++) {
                float b[4];
                *(float4*)b = *(const float4*)(sc1W1 + (size_t)(kc + kk) * 128 + tx * 4);
#pragma unroll
                for (int j = 0; j < 4; j++) acc3[j] += af[kk] * b[j];
            }
        }
        float h[4];
#pragma unroll
        for (int j = 0; j < 4; j++) h[j] = silu_f(acc3[j] + sc1b1[tx * 4 + j]);
        __syncthreads();                // all AsL reads done before overwrite
        *(float4*)&workS[ty * AS + tx * 4] = *(float4*)h;
    }
    __syncthreads();

    // ---------- stage 4: x1 = hmid @ sc1W2 + b2, K=128 ----------------------
    float xg[4];
    {
        float acc4[4];
#pragma unroll
        for (int j = 0; j < 4; j++) acc4[j] = 0.0f;
        for (int kc = 0; kc < 128; kc += 8) {
            float af[8];
            *(float4*)&af[0] = *(const float4*)&workS[ty * AS + kc];
            *(float4*)&af[4] = *(const float4*)&workS[ty * AS + kc + 4];
#pragma unroll
            for (int kk = 0; kk < 8; kk++) {
                float b[4];
                *(float4*)b = *(const float4*)(sc1W2 + (size_t)(kc + kk) * 128 + tx * 4);
#pragma unroll
                for (int j = 0; j < 4; j++) acc4[j] += af[kk] * b[j];
            }
        }
        if (tx < 16) {                  // s-half -> LDS (raw; silu in 5b)
            float xs[4];
#pragma unroll
            for (int j = 0; j < 4; j++) xs[j] = acc4[j] + sc1b2[tx * 4 + j];
            *(float4*)&xinS[ty * XS + tx * 4] = *(float4*)xs;
        } else {                        // gate cols 64..127 stay in regs
#pragma unroll
            for (int j = 0; j < 4; j++) xg[j] = acc4[j] + sc1b2[tx * 4 + j];
        }
    }

    // ---------- stage 5a: vW*gate . mixW2, 16-lane reduction ----------------
    if (tx >= 16) {
        const int hc = (tx - 16) * 4;   // mixW2 row base
        float p0 = 0, p1 = 0, p2 = 0, p3 = 0, p4 = 0, p5 = 0;
#pragma unroll
        for (int c = 0; c < 4; c++) {
            float2 m = *(const float2*)(mixW2 + (size_t)(hc + c) * 2);
            const float v0 = xg[c] * acc[0][c];
            const float v1 = xg[c] * acc[1][c];
            const float v2 = xg[c] * acc[2][c];
            p0 += v0 * m.x; p1 += v0 * m.y;
            p2 += v1 * m.x; p3 += v1 * m.y;
            p4 += v2 * m.x; p5 += v2 * m.y;
        }
        RED16(p0); RED16(p1); RED16(p2); RED16(p3); RED16(p4); RED16(p5);
        if (tx == 16) {
            vn2s[ty] = sqrtf(p0 * p0 + p2 * p2 + p4 * p4);
            pw2s[ty][0] = p1; pw2s[ty][1] = p3; pw2s[ty][2] = p5;
        }
    }
    __syncthreads();

    // ---------- stage 5b: block-2 MLP (64-wide) per node --------------------
    {
        const int w = t >> 6, lane = t & 63;
        const float bb1 = sc2b1[lane];
        const float wn  = sc2W1[64 * 64 + lane];
        const float wq0 = sc2W2[lane * 2 + 0], wq1 = sc2W2[lane * 2 + 1];
#pragma unroll
        for (int r = 0; r < 2; r++) {
            const int nl = r * 4 + w;
            const float s1 = silu_f(xinS[nl * XS + lane]);
            s1s[w][lane] = s1;
            __builtin_amdgcn_s_waitcnt(0);   // lgkmcnt(0): own-wave LDS visible
            float acc5 = bb1 + vn2s[nl] * wn;
#pragma unroll 8
            for (int i2 = 0; i2 < 64; i2++) acc5 += s1s[w][i2] * sc2W1[i2 * 64 + lane];
            const float h2 = silu_f(acc5);
            float q0 = h2 * wq0, q1 = h2 * wq1;
            RED64(q0); RED64(q1);
            if (lane == 0) {
                const int n = node0 + nl;
                const float gate = q1 + sc2b2[1];
                l0v[n] = q0 + sc2b2[0];
                l1v[(size_t)n * 3 + 0] = gate * pw2s[nl][0];
                l1v[(size_t)n * 3 + 1] = gate * pw2s[nl][1];
                l1v[(size_t)n * 3 + 2] = gate * pw2s[nl][2];
            }
        }
    }
}

// ---------- pairpre: j-parallel P-tables, coalesced stores ------------------
__global__ __launch_bounds__(256)
void pairpre_k(const float* __restrict__ l1v, const float* __restrict__ pos,
               const float* __restrict__ l0v,
               const float* __restrict__ vvW1, const float* __restrict__ vrW1,
               const float* __restrict__ sW1, const float* __restrict__ sb1,
               float* __restrict__ Pv, float* __restrict__ Pr,
               float* __restrict__ Ps) {
    const int j = blockIdx.x * 256 + threadIdx.x;
    const float lj0 = l1v[j * 3 + 0], lj1 = l1v[j * 3 + 1], lj2 = l1v[j * 3 + 2];
    const float pj0 = pos[j * 3 + 0], pj1 = pos[j * 3 + 1], pj2 = pos[j * 3 + 2];
    const float l0j = l0v[j];
    for (int h = 0; h < 30; h++) {
#pragma unroll
        for (int a = 0; a < 3; a++) {
            float v = lj0 * vvW1[(3 * a + 0) * 30 + h] + lj1 * vvW1[(3 * a + 1) * 30 + h]
                    + lj2 * vvW1[(3 * a + 2) * 30 + h];
            float r = pj0 * vrW1[(3 * a + 0) * 30 + h] + pj1 * vrW1[(3 * a + 1) * 30 + h]
                    + pj2 * vrW1[(3 * a + 2) * 30 + h];
            Pv[(size_t)(a * 30 + h) * NNODES + j] = v;
            Pr[(size_t)(a * 30 + h) * NNODES + j] = r;
        }
        Ps[(size_t)h * NNODES + j] = sb1[h] + l0j * sW1[30 + h];
    }
}

// ---------------- pair kernel: factorized MLPs, rolled h-loops --------------
__global__ __launch_bounds__(192)
void pair_k(const float* __restrict__ l0v, const float* __restrict__ l1v,
            const float* __restrict__ Pv, const float* __restrict__ Pr,
            const float* __restrict__ Ps,
            const float* __restrict__ vvb1, const float* __restrict__ vrb1,
            const float* __restrict__ sW1,
            const float* __restrict__ vvW2, const float* __restrict__ vrW2,
            const float* __restrict__ sW2,
            const float* __restrict__ vvb2, const float* __restrict__ vrb2,
            const float* __restrict__ sb2,
            const float* __restrict__ hW1,  const float* __restrict__ hb1,
            const float* __restrict__ hW2,  const float* __restrict__ hb2,
            float* __restrict__ out) {
    const int t = threadIdx.x;
    const int b = blockIdx.y;
    const int di = (t >= 96) ? 1 : 0;
    const int i = blockIdx.x * 2 + di;
    const int j = t - di * 96;
    const int ni = b * A_ATOMS + i;
    const int nj = b * A_ATOMS + j;

    const float li0 = l1v[ni * 3 + 0], li1 = l1v[ni * 3 + 1], li2 = l1v[ni * 3 + 2];
    const float s0i = l0v[ni];

    float t9[9];
#pragma unroll
    for (int l = 0; l < 9; l++) t9[l] = vvb2[l] + vrb2[l] + sb2[l];

    for (int h = 0; h < 30; h++) {
        float av = vvb1[h] + li0 * Pv[(size_t)h * NNODES + nj]
                           + li1 * Pv[(size_t)(30 + h) * NNODES + nj]
                           + li2 * Pv[(size_t)(60 + h) * NNODES + nj];
        float ar = vrb1[h] + li0 * Pr[(size_t)h * NNODES + nj]
                           + li1 * Pr[(size_t)(30 + h) * NNODES + nj]
                           + li2 * Pr[(size_t)(60 + h) * NNODES + nj];
        float as = Ps[(size_t)h * NNODES + nj] + s0i * sW1[h];
        av = silu_f(av); ar = silu_f(ar); as = silu_f(as);
#pragma unroll
        for (int l = 0; l < 9; l++)
            t9[l] += av * vvW2[h * 9 + l] + ar * vrW2[h * 9 + l] + as * sW2[h * 9 + l];
    }

    float o9[9];
#pragma unroll
    for (int l = 0; l < 9; l++) o9[l] = hb2[l];
    for (int h = 0; h < 30; h++) {
        float a = hb1[h];
#pragma unroll
        for (int m = 0; m < 9; m++) a += t9[m] * hW1[m * 30 + h];
        a = silu_f(a);
#pragma unroll
        for (int l = 0; l < 9; l++) o9[l] += a * hW2[h * 9 + l];
    }

    // out[((b*A+i)*3+k)*288 + j*3 + l] = o9[3k+l]
    const size_t rb = (size_t)(b * A_ATOMS + i);
#pragma unroll
    for (int k = 0; k < 3; k++) {
        const size_t off = (rb * 3 + k) * 288 + (size_t)j * 3;
        out[off + 0] = o9[3 * k + 0];
        out[off + 1] = o9[3 * k + 1];
        out[off + 2] = o9[3 * k + 2];
    }
}

extern "C" void kernel_launch(void* const* d_in, const int* in_sizes, int n_in,
                              void* d_out, int out_size, void* d_ws, size_t ws_size,
                              hipStream_t stream) {
    const float* pos   = (const float*)d_in[0];
    const float* srep  = (const float*)d_in[1];
    const float* vrep  = (const float*)d_in[2];
    const float* mixW1 = (const float*)d_in[3];
    const float* sc1W1 = (const float*)d_in[4];
    const float* sc1b1 = (const float*)d_in[5];
    const float* sc1W2 = (const float*)d_in[6];
    const float* sc1b2 = (const float*)d_in[7];
    const float* mixW2 = (const float*)d_in[8];
    const float* sc2W1 = (const float*)d_in[9];
    const float* sc2b1 = (const float*)d_in[10];
    const float* sc2W2 = (const float*)d_in[11];
    const float* sc2b2 = (const float*)d_in[12];
    const float* vvW1  = (const float*)d_in[13];
    const float* vvb1  = (const float*)d_in[14];
    const float* vvW2  = (const float*)d_in[15];
    const float* vvb2  = (const float*)d_in[16];
    const float* vrW1  = (const float*)d_in[17];
    const float* vrb1  = (const float*)d_in[18];
    const float* vrW2  = (const float*)d_in[19];
    const float* vrb2  = (const float*)d_in[20];
    const float* sW1   = (const float*)d_in[21];
    const float* sb1   = (const float*)d_in[22];
    const float* sW2   = (const float*)d_in[23];
    const float* sb2   = (const float*)d_in[24];
    const float* hW1   = (const float*)d_in[25];
    const float* hb1   = (const float*)d_in[26];
    const float* hW2   = (const float*)d_in[27];
    const float* hb2   = (const float*)d_in[28];

    float* ws  = (float*)d_ws;
    float* Pv  = ws;                    // 90*12288 = 1,105,920
    float* Pr  = Pv + 1105920;          // 1,105,920
    float* Ps  = Pr + 1105920;          // 30*12288 = 368,640
    float* l0v = Ps + 368640;           // 12,288
    float* l1v = l0v + 12288;           // 36,864
    float* outf = (float*)d_out;

    // 1. fused node stage -> l0, l1
    node_k<<<NNODES / NB, 256, 0, stream>>>(
        vrep, mixW1, srep,
        sc1W1, sc1b1, sc1W2, sc1b2,
        mixW2, sc2W1, sc2b1, sc2W2, sc2b2,
        l0v, l1v);

    // 2. P-tables (coalesced j-major stores)
    pairpre_k<<<NNODES / 256, 256, 0, stream>>>(l1v, pos, l0v, vvW1, vrW1,
                                                sW1, sb1, Pv, Pr, Ps);

    // 3. pair stage
    pair_k<<<dim3(A_ATOMS / 2, BATCH), 192, 0, stream>>>(
        l0v, l1v, Pv, Pr, Ps,
        vvb1, vrb1, sW1,
        vvW2, vrW2, sW2,
        vvb2, vrb2, sb2,
        hW1, hb1, hW2, hb2,
        outf);
}

// Round 7
// 298.432 us; speedup vs baseline: 1.0876x; 1.0717x over previous
//
#include <hip/hip_runtime.h>
#include <cstddef>

#define A_ATOMS 96
#define BATCH   128
#define NNODES  12288   // B*A
#define NB      8       // nodes per block (node_k)
#define AS      132     // AsL / workS stride (132%32=4)
#define XS      196     // xinS stride (196%32=4)

typedef float v2f __attribute__((ext_vector_type(2)));

__device__ __forceinline__ float silu_f(float x) {
    float e = __expf(-x);
    return x * __builtin_amdgcn_rcpf(1.0f + e);
}
__device__ __forceinline__ v2f silu2(v2f x) {
    v2f r; r.x = silu_f(x.x); r.y = silu_f(x.y); return r;
}

#define RED64(v) { v += __shfl_xor(v, 1); v += __shfl_xor(v, 2); v += __shfl_xor(v, 4); \
                   v += __shfl_xor(v, 8); v += __shfl_xor(v, 16); v += __shfl_xor(v, 32); }
#define RED16(v) { v += __shfl_xor(v, 1); v += __shfl_xor(v, 2); v += __shfl_xor(v, 4); \
                   v += __shfl_xor(v, 8); }

// ===== fused node kernel (unchanged from R6): 8 nodes/block, 1536 blocks ====
__global__ __launch_bounds__(256)
void node_k(const float* __restrict__ vrep, const float* __restrict__ mixW1,
            const float* __restrict__ srep,
            const float* __restrict__ sc1W1, const float* __restrict__ sc1b1,
            const float* __restrict__ sc1W2, const float* __restrict__ sc1b2,
            const float* __restrict__ mixW2,
            const float* __restrict__ sc2W1, const float* __restrict__ sc2b1,
            const float* __restrict__ sc2W2, const float* __restrict__ sc2b2,
            float* __restrict__ l0v, float* __restrict__ l1v) {
    __shared__ float AsL[24 * AS];
    __shared__ float xinS[NB * XS];
    __shared__ float s1s[4][64];
    __shared__ float vn2s[NB];
    __shared__ float pw2s[NB][3];

    const int t  = threadIdx.x;
    const int tx = t & 31;
    const int ty = t >> 5;
    const int row0  = blockIdx.x * 24;
    const int node0 = blockIdx.x * NB;

#pragma unroll
    for (int it = 0; it < 3; it++) {
        const int idx = it * 256 + t;
        const int r   = idx >> 5;
        const int c4  = (idx & 31) * 4;
        *(float4*)&AsL[r * AS + c4] = *(const float4*)(vrep + (size_t)(row0 + r) * 128 + c4);
    }
    {
        const int a  = t >> 5;
        const int c4 = (t & 31) * 4;
        *(float4*)&xinS[a * XS + c4] = *(const float4*)(srep + (size_t)(node0 + a) * 128 + c4);
    }
    __syncthreads();

    float acc[3][4];
#pragma unroll
    for (int i = 0; i < 3; i++)
#pragma unroll
        for (int j = 0; j < 4; j++) acc[i][j] = 0.0f;

    for (int kc = 0; kc < 128; kc += 8) {
        float a0[8], a1[8], a2[8];
        *(float4*)&a0[0] = *(const float4*)&AsL[(3 * ty + 0) * AS + kc];
        *(float4*)&a0[4] = *(const float4*)&AsL[(3 * ty + 0) * AS + kc + 4];
        *(float4*)&a1[0] = *(const float4*)&AsL[(3 * ty + 1) * AS + kc];
        *(float4*)&a1[4] = *(const float4*)&AsL[(3 * ty + 1) * AS + kc + 4];
        *(float4*)&a2[0] = *(const float4*)&AsL[(3 * ty + 2) * AS + kc];
        *(float4*)&a2[4] = *(const float4*)&AsL[(3 * ty + 2) * AS + kc + 4];
#pragma unroll
        for (int kk = 0; kk < 8; kk++) {
            float b[4];
            *(float4*)b = *(const float4*)(mixW1 + (size_t)(kc + kk) * 128 + tx * 4);
#pragma unroll
            for (int j = 0; j < 4; j++) {
                acc[0][j] += a0[kk] * b[j];
                acc[1][j] += a1[kk] * b[j];
                acc[2][j] += a2[kk] * b[j];
            }
        }
    }
    if (tx < 16) {
        float nrm[4];
#pragma unroll
        for (int c = 0; c < 4; c++)
            nrm[c] = sqrtf(acc[0][c] * acc[0][c] + acc[1][c] * acc[1][c]
                         + acc[2][c] * acc[2][c]);
        *(float4*)&xinS[ty * XS + 128 + tx * 4] = *(float4*)nrm;
    }
    __syncthreads();

    float* workS = AsL;
    {
        float acc3[4];
#pragma unroll
        for (int j = 0; j < 4; j++) acc3[j] = 0.0f;
        for (int kc = 0; kc < 192; kc += 8) {
            float af[8];
            *(float4*)&af[0] = *(const float4*)&xinS[ty * XS + kc];
            *(float4*)&af[4] = *(const float4*)&xinS[ty * XS + kc + 4];
#pragma unroll
            for (int kk = 0; kk < 8; kk++) {
                float b[4];
                *(float4*)b = *(const float4*)(sc1W1 + (size_t)(kc + kk) * 128 + tx * 4);
#pragma unroll
                for (int j = 0; j < 4; j++) acc3[j] += af[kk] * b[j];
            }
        }
        float h[4];
#pragma unroll
        for (int j = 0; j < 4; j++) h[j] = silu_f(acc3[j] + sc1b1[tx * 4 + j]);
        __syncthreads();
        *(float4*)&workS[ty * AS + tx * 4] = *(float4*)h;
    }
    __syncthreads();

    float xg[4];
    {
        float acc4[4];
#pragma unroll
        for (int j = 0; j < 4; j++) acc4[j] = 0.0f;
        for (int kc = 0; kc < 128; kc += 8) {
            float af[8];
            *(float4*)&af[0] = *(const float4*)&workS[ty * AS + kc];
            *(float4*)&af[4] = *(const float4*)&workS[ty * AS + kc + 4];
#pragma unroll
            for (int kk = 0; kk < 8; kk++) {
                float b[4];
                *(float4*)b = *(const float4*)(sc1W2 + (size_t)(kc + kk) * 128 + tx * 4);
#pragma unroll
                for (int j = 0; j < 4; j++) acc4[j] += af[kk] * b[j];
            }
        }
        if (tx < 16) {
            float xs[4];
#pragma unroll
            for (int j = 0; j < 4; j++) xs[j] = acc4[j] + sc1b2[tx * 4 + j];
            *(float4*)&xinS[ty * XS + tx * 4] = *(float4*)xs;
        } else {
#pragma unroll
            for (int j = 0; j < 4; j++) xg[j] = acc4[j] + sc1b2[tx * 4 + j];
        }
    }

    if (tx >= 16) {
        const int hc = (tx - 16) * 4;
        float p0 = 0, p1 = 0, p2 = 0, p3 = 0, p4 = 0, p5 = 0;
#pragma unroll
        for (int c = 0; c < 4; c++) {
            float2 m = *(const float2*)(mixW2 + (size_t)(hc + c) * 2);
            const float v0 = xg[c] * acc[0][c];
            const float v1 = xg[c] * acc[1][c];
            const float v2 = xg[c] * acc[2][c];
            p0 += v0 * m.x; p1 += v0 * m.y;
            p2 += v1 * m.x; p3 += v1 * m.y;
            p4 += v2 * m.x; p5 += v2 * m.y;
        }
        RED16(p0); RED16(p1); RED16(p2); RED16(p3); RED16(p4); RED16(p5);
        if (tx == 16) {
            vn2s[ty] = sqrtf(p0 * p0 + p2 * p2 + p4 * p4);
            pw2s[ty][0] = p1; pw2s[ty][1] = p3; pw2s[ty][2] = p5;
        }
    }
    __syncthreads();

    {
        const int w = t >> 6, lane = t & 63;
        const float bb1 = sc2b1[lane];
        const float wn  = sc2W1[64 * 64 + lane];
        const float wq0 = sc2W2[lane * 2 + 0], wq1 = sc2W2[lane * 2 + 1];
#pragma unroll
        for (int r = 0; r < 2; r++) {
            const int nl = r * 4 + w;
            const float s1 = silu_f(xinS[nl * XS + lane]);
            s1s[w][lane] = s1;
            __builtin_amdgcn_s_waitcnt(0);
            float acc5 = bb1 + vn2s[nl] * wn;
#pragma unroll 8
            for (int i2 = 0; i2 < 64; i2++) acc5 += s1s[w][i2] * sc2W1[i2 * 64 + lane];
            const float h2 = silu_f(acc5);
            float q0 = h2 * wq0, q1 = h2 * wq1;
            RED64(q0); RED64(q1);
            if (lane == 0) {
                const int n = node0 + nl;
                const float gate = q1 + sc2b2[1];
                l0v[n] = q0 + sc2b2[0];
                l1v[(size_t)n * 3 + 0] = gate * pw2s[nl][0];
                l1v[(size_t)n * 3 + 1] = gate * pw2s[nl][1];
                l1v[(size_t)n * 3 + 2] = gate * pw2s[nl][2];
            }
        }
    }
}

// ---------- pairpre v2: 384 blocks (32 j x 8 h-groups), coalesced stores ----
__global__ __launch_bounds__(256)
void pairpre_k(const float* __restrict__ l1v, const float* __restrict__ pos,
               const float* __restrict__ l0v,
               const float* __restrict__ vvW1, const float* __restrict__ vrW1,
               const float* __restrict__ sW1, const float* __restrict__ sb1,
               float* __restrict__ Pv, float* __restrict__ Pr,
               float* __restrict__ Ps) {
    const int jl = threadIdx.x & 31;
    const int hq = threadIdx.x >> 5;        // 0..7
    const int j  = blockIdx.x * 32 + jl;
    const float lj0 = l1v[j * 3 + 0], lj1 = l1v[j * 3 + 1], lj2 = l1v[j * 3 + 2];
    const float pj0 = pos[j * 3 + 0], pj1 = pos[j * 3 + 1], pj2 = pos[j * 3 + 2];
    const float l0j = l0v[j];
#pragma unroll
    for (int hh = 0; hh < 4; hh++) {
        const int h = hq * 4 + hh;
        if (h < 30) {
#pragma unroll
            for (int a = 0; a < 3; a++) {
                float v = lj0 * vvW1[(3 * a + 0) * 30 + h] + lj1 * vvW1[(3 * a + 1) * 30 + h]
                        + lj2 * vvW1[(3 * a + 2) * 30 + h];
                float r = pj0 * vrW1[(3 * a + 0) * 30 + h] + pj1 * vrW1[(3 * a + 1) * 30 + h]
                        + pj2 * vrW1[(3 * a + 2) * 30 + h];
                Pv[(size_t)(a * 30 + h) * NNODES + j] = v;
                Pr[(size_t)(a * 30 + h) * NNODES + j] = r;
            }
            Ps[(size_t)h * NNODES + j] = sb1[h] + l0j * sW1[30 + h];
        }
    }
}

// ---------- pair kernel v3: 2 i-atoms per thread, packed f32 (v_pk_fma) -----
// Grid (A/4, B), 192 threads: t -> g=t/96 (i-pair), j=t%96; i = bx*4+2g+{0,1}.
__global__ __launch_bounds__(192)
void pair_k(const float* __restrict__ l0v, const float* __restrict__ l1v,
            const float* __restrict__ Pv, const float* __restrict__ Pr,
            const float* __restrict__ Ps,
            const float* __restrict__ vvb1, const float* __restrict__ vrb1,
            const float* __restrict__ sW1,
            const float* __restrict__ vvW2, const float* __restrict__ vrW2,
            const float* __restrict__ sW2,
            const float* __restrict__ vvb2, const float* __restrict__ vrb2,
            const float* __restrict__ sb2,
            const float* __restrict__ hW1,  const float* __restrict__ hb1,
            const float* __restrict__ hW2,  const float* __restrict__ hb2,
            float* __restrict__ out) {
    const int t = threadIdx.x;
    const int b = blockIdx.y;
    const int g = (t >= 96) ? 1 : 0;
    const int j = t - g * 96;
    const int i0 = blockIdx.x * 4 + g * 2;
    const int ni0 = b * A_ATOMS + i0;
    const int ni1 = ni0 + 1;
    const int nj  = b * A_ATOMS + j;

    const v2f li0 = { l1v[ni0 * 3 + 0], l1v[ni1 * 3 + 0] };
    const v2f li1 = { l1v[ni0 * 3 + 1], l1v[ni1 * 3 + 1] };
    const v2f li2 = { l1v[ni0 * 3 + 2], l1v[ni1 * 3 + 2] };
    const v2f s0i = { l0v[ni0], l0v[ni1] };

    v2f t9[9];
#pragma unroll
    for (int l = 0; l < 9; l++) t9[l] = (v2f)(vvb2[l] + vrb2[l] + sb2[l]);

    for (int h = 0; h < 30; h++) {
        const float pv0 = Pv[(size_t)h * NNODES + nj];
        const float pv1 = Pv[(size_t)(30 + h) * NNODES + nj];
        const float pv2 = Pv[(size_t)(60 + h) * NNODES + nj];
        const float pr0 = Pr[(size_t)h * NNODES + nj];
        const float pr1 = Pr[(size_t)(30 + h) * NNODES + nj];
        const float pr2 = Pr[(size_t)(60 + h) * NNODES + nj];
        const float ps  = Ps[(size_t)h * NNODES + nj];

        v2f av = (v2f)(vvb1[h]) + li0 * pv0 + li1 * pv1 + li2 * pv2;
        v2f ar = (v2f)(vrb1[h]) + li0 * pr0 + li1 * pr1 + li2 * pr2;
        v2f as = (v2f)(ps) + s0i * sW1[h];
        av = silu2(av); ar = silu2(ar); as = silu2(as);
#pragma unroll
        for (int l = 0; l < 9; l++)
            t9[l] += av * vvW2[h * 9 + l] + ar * vrW2[h * 9 + l] + as * sW2[h * 9 + l];
    }

    v2f o9[9];
#pragma unroll
    for (int l = 0; l < 9; l++) o9[l] = (v2f)(hb2[l]);
    for (int h = 0; h < 30; h++) {
        v2f a = (v2f)(hb1[h]);
#pragma unroll
        for (int m = 0; m < 9; m++) a += t9[m] * hW1[m * 30 + h];
        a = silu2(a);
#pragma unroll
        for (int l = 0; l < 9; l++) o9[l] += a * hW2[h * 9 + l];
    }

    // out[((b*A+i)*3+k)*288 + j*3 + l]
    const size_t rb0 = (size_t)ni0;
#pragma unroll
    for (int k = 0; k < 3; k++) {
        const size_t off0 = (rb0 * 3 + k) * 288 + (size_t)j * 3;
        const size_t off1 = off0 + 3 * 288;
        out[off0 + 0] = o9[3 * k + 0].x;
        out[off0 + 1] = o9[3 * k + 1].x;
        out[off0 + 2] = o9[3 * k + 2].x;
        out[off1 + 0] = o9[3 * k + 0].y;
        out[off1 + 1] = o9[3 * k + 1].y;
        out[off1 + 2] = o9[3 * k + 2].y;
    }
}

extern "C" void kernel_launch(void* const* d_in, const int* in_sizes, int n_in,
                              void* d_out, int out_size, void* d_ws, size_t ws_size,
                              hipStream_t stream) {
    const float* pos   = (const float*)d_in[0];
    const float* srep  = (const float*)d_in[1];
    const float* vrep  = (const float*)d_in[2];
    const float* mixW1 = (const float*)d_in[3];
    const float* sc1W1 = (const float*)d_in[4];
    const float* sc1b1 = (const float*)d_in[5];
    const float* sc1W2 = (const float*)d_in[6];
    const float* sc1b2 = (const float*)d_in[7];
    const float* mixW2 = (const float*)d_in[8];
    const float* sc2W1 = (const float*)d_in[9];
    const float* sc2b1 = (const float*)d_in[10];
    const float* sc2W2 = (const float*)d_in[11];
    const float* sc2b2 = (const float*)d_in[12];
    const float* vvW1  = (const float*)d_in[13];
    const float* vvb1  = (const float*)d_in[14];
    const float* vvW2  = (const float*)d_in[15];
    const float* vvb2  = (const float*)d_in[16];
    const float* vrW1  = (const float*)d_in[17];
    const float* vrb1  = (const float*)d_in[18];
    const float* vrW2  = (const float*)d_in[19];
    const float* vrb2  = (const float*)d_in[20];
    const float* sW1   = (const float*)d_in[21];
    const float* sb1   = (const float*)d_in[22];
    const float* sW2   = (const float*)d_in[23];
    const float* sb2   = (const float*)d_in[24];
    const float* hW1   = (const float*)d_in[25];
    const float* hb1   = (const float*)d_in[26];
    const float* hW2   = (const float*)d_in[27];
    const float* hb2   = (const float*)d_in[28];

    float* ws  = (float*)d_ws;
    float* Pv  = ws;                    // 90*12288 = 1,105,920
    float* Pr  = Pv + 1105920;          // 1,105,920
    float* Ps  = Pr + 1105920;          // 30*12288 = 368,640
    float* l0v = Ps + 368640;           // 12,288
    float* l1v = l0v + 12288;           // 36,864
    float* outf = (float*)d_out;

    // 1. fused node stage -> l0, l1
    node_k<<<NNODES / NB, 256, 0, stream>>>(
        vrep, mixW1, srep,
        sc1W1, sc1b1, sc1W2, sc1b2,
        mixW2, sc2W1, sc2b1, sc2W2, sc2b2,
        l0v, l1v);

    // 2. P-tables (coalesced j-major stores, 384 blocks)
    pairpre_k<<<NNODES / 32, 256, 0, stream>>>(l1v, pos, l0v, vvW1, vrW1,
                                               sW1, sb1, Pv, Pr, Ps);

    // 3. pair stage (2 i per thread, packed f32)
    pair_k<<<dim3(A_ATOMS / 4, BATCH), 192, 0, stream>>>(
        l0v, l1v, Pv, Pr, Ps,
        vvb1, vrb1, sW1,
        vvW2, vrW2, sW2,
        vvb2, vrb2, sb2,
        hW1, hb1, hW2, hb2,
        outf);
}